// Round 3
// baseline (473.437 us; speedup 1.0000x reference)
//
#include <hip/hip_runtime.h>

#define HIDDEN 64
#define NREL 50
#define NPAIR (NREL * NREL)
#define K_INL 6           // inline slots in recA: {u32 cnt; u16 s[6]} = 16 B
#define K_SLOTS 30        // total capacity (6 inline + 24 overflow), clamp as before

typedef int   iv4 __attribute__((ext_vector_type(4)));
typedef float fv4 __attribute__((ext_vector_type(4)));

// ---------------------------------------------------------------------------
// Kernel 1: precompute tables + u8 relation copy.
//   M2[p][j] = sum_k relu( sum_i pair_p[i] * W_msg[i][k] ) * W_upd[64+k][j]
//   Hc[r][j] = sum_i rel_emb[r][i] * W_upd[i][j]
//   rel8[e]  = (u8)rel[e]
// ---------------------------------------------------------------------------
__global__ void precompute_tables(const float* __restrict__ rel_emb,
                                  const float* __restrict__ W_msg,
                                  const float* __restrict__ W_upd,
                                  const int* __restrict__ rel,
                                  unsigned char* __restrict__ rel8,
                                  int conv_n,
                                  float* __restrict__ M2,
                                  float* __restrict__ Hc) {
    const int p = blockIdx.x;      // 0..2499
    const int j = threadIdx.x;     // 0..63

    for (int i = p * HIDDEN + j; i < conv_n; i += NPAIR * HIDDEN)
        rel8[i] = (unsigned char)rel[i];

    const int ra = p / NREL, rb = p % NREL;
    __shared__ float msg[HIDDEN];
    const float* ha = rel_emb + ra * HIDDEN;
    const float* hb = rel_emb + rb * HIDDEN;

    float acc = 0.f;
    #pragma unroll 8
    for (int i = 0; i < HIDDEN; ++i) acc += ha[i] * W_msg[i * HIDDEN + j];
    #pragma unroll 8
    for (int i = 0; i < HIDDEN; ++i) acc += hb[i] * W_msg[(HIDDEN + i) * HIDDEN + j];
    msg[j] = fmaxf(acc, 0.f);
    __syncthreads();

    float acc2 = 0.f;
    #pragma unroll 8
    for (int k = 0; k < HIDDEN; ++k) acc2 += msg[k] * W_upd[(HIDDEN + k) * HIDDEN + j];
    M2[p * HIDDEN + j] = acc2;

    if (p < NREL) {
        float acc3 = 0.f;
        #pragma unroll 8
        for (int i = 0; i < HIDDEN; ++i) acc3 += rel_emb[p * HIDDEN + i] * W_upd[i * HIDDEN + j];
        Hc[p * HIDDEN + j] = acc3;
    }
}

// ---------------------------------------------------------------------------
// Kernel 2: record scatter, 8 triangles/thread for atomic MLP.
// recA[e] = {u32 cnt; u16 s[6]} (16 B, pre-zeroed). Ranks 6..29 spill to
// recB[e][24] (never memset: only read where written).
// Phase order per thread: all loads -> all gathers -> ALL 8 atomics -> stores,
// so 8 far-atomic round trips overlap instead of serializing.
// ---------------------------------------------------------------------------
__global__ __launch_bounds__(256) void hist_record(
        const unsigned char* __restrict__ rel8,
        const int* __restrict__ edge_ab,
        const int* __restrict__ edge_bc,
        const int* __restrict__ edge_ac,
        unsigned int* __restrict__ recA,
        unsigned short* __restrict__ recB,
        int num_tri) {
    const int n8 = num_tri >> 3;
    int i = blockIdx.x * blockDim.x + threadIdx.x;
    const int stride = gridDim.x * blockDim.x;
    for (; i < n8; i += stride) {
        const iv4 a0 = __builtin_nontemporal_load((const iv4*)edge_ab + 2 * i);
        const iv4 a1 = __builtin_nontemporal_load((const iv4*)edge_ab + 2 * i + 1);
        const iv4 b0 = __builtin_nontemporal_load((const iv4*)edge_bc + 2 * i);
        const iv4 b1 = __builtin_nontemporal_load((const iv4*)edge_bc + 2 * i + 1);
        const iv4 c0 = __builtin_nontemporal_load((const iv4*)edge_ac + 2 * i);
        const iv4 c1 = __builtin_nontemporal_load((const iv4*)edge_ac + 2 * i + 1);
        int p[8], c[8];
        #pragma unroll
        for (int k = 0; k < 4; ++k) {
            p[k]     = (int)rel8[a0[k]] * NREL + (int)rel8[b0[k]];
            p[k + 4] = (int)rel8[a1[k]] * NREL + (int)rel8[b1[k]];
            c[k]     = c0[k];
            c[k + 4] = c1[k];
        }
        unsigned int r[8];
        #pragma unroll
        for (int k = 0; k < 8; ++k)
            r[k] = atomicAdd(recA + ((size_t)c[k] << 2), 1u);
        #pragma unroll
        for (int k = 0; k < 8; ++k) {
            if (r[k] < K_INL)
                ((unsigned short*)(recA + ((size_t)c[k] << 2) + 1))[r[k]] = (unsigned short)p[k];
            else if (r[k] < K_SLOTS)
                recB[(size_t)c[k] * 24 + (r[k] - K_INL)] = (unsigned short)p[k];
        }
    }
    // tail (num_tri % 8), handled by the last block
    const int rem = num_tri & 7;
    if (rem && blockIdx.x == gridDim.x - 1 && threadIdx.x < rem) {
        const int t = (num_tri & ~7) + threadIdx.x;
        const int p = (int)rel8[edge_ab[t]] * NREL + (int)rel8[edge_bc[t]];
        const size_t c = (size_t)edge_ac[t];
        const unsigned int r = atomicAdd(recA + (c << 2), 1u);
        if (r < K_INL) ((unsigned short*)(recA + (c << 2) + 1))[r] = (unsigned short)p;
        else if (r < K_SLOTS) recB[c * 24 + (r - K_INL)] = (unsigned short)p;
    }
}

// ---------------------------------------------------------------------------
// Kernel 3: per-edge gather-accumulate + fused update.
// One int4 load delivers count AND all common-case slots -> the 6 M2 gathers
// issue immediately (no dependent u16 chain). Next iteration's record+rel8
// are prefetched before this iteration's gathers (software pipeline).
// ---------------------------------------------------------------------------
__global__ __launch_bounds__(256) void accumulate_record(
        const unsigned char* __restrict__ rel8,
        const unsigned int* __restrict__ recA,
        const unsigned short* __restrict__ recB,
        const float* __restrict__ M2,
        const float* __restrict__ Hc,
        float* __restrict__ out, int num_edge) {
    const int sub = threadIdx.x >> 4;   // edge slot within block
    const int l   = threadIdx.x & 15;   // float4 lane within row
    const int estride = gridDim.x * 16;
    int e = blockIdx.x * 16 + sub;
    if (e >= num_edge) return;
    iv4 w = __builtin_nontemporal_load((const iv4*)recA + e);
    int re = rel8[e];
    while (true) {
        const int en = e + estride;
        const bool more = en < num_edge;
        iv4 wn = {};
        int rn = 0;
        if (more) {                      // prefetch next iteration
            wn = __builtin_nontemporal_load((const iv4*)recA + en);
            rn = rel8[en];
        }
        const int dc  = w.x;
        const int deg = dc < K_SLOTS ? dc : K_SLOTS;
        fv4 acc0 = ((const fv4*)(Hc + re * HIDDEN))[l];
        fv4 acc1 = (fv4)0.f;
        const int s0 = w.y & 0xFFFF, s1 = ((unsigned)w.y) >> 16;
        const int s2 = w.z & 0xFFFF, s3 = ((unsigned)w.z) >> 16;
        const int s4 = w.w & 0xFFFF, s5 = ((unsigned)w.w) >> 16;
        if (deg > 0) acc0 += ((const fv4*)M2)[s0 * 16 + l];
        if (deg > 1) acc1 += ((const fv4*)M2)[s1 * 16 + l];
        if (deg > 2) acc0 += ((const fv4*)M2)[s2 * 16 + l];
        if (deg > 3) acc1 += ((const fv4*)M2)[s3 * 16 + l];
        if (deg > 4) acc0 += ((const fv4*)M2)[s4 * 16 + l];
        if (deg > 5) acc1 += ((const fv4*)M2)[s5 * 16 + l];
        if (deg > K_INL) {               // rare (~0.4% of edges)
            for (int k = K_INL; k < deg; ++k) {
                const int p = recB[(size_t)e * 24 + (k - K_INL)];
                acc0 += ((const fv4*)M2)[p * 16 + l];
            }
        }
        fv4 o = acc0 + acc1;
        o.x = fmaxf(o.x, 0.f);
        o.y = fmaxf(o.y, 0.f);
        o.z = fmaxf(o.z, 0.f);
        o.w = fmaxf(o.w, 0.f);
        __builtin_nontemporal_store(o, (fv4*)out + (size_t)e * 16 + l);
        if (!more) break;
        e = en; w = wn; re = rn;
    }
}

// --------------------------- fallback (atomic) path ------------------------
__global__ void scatter_tri(const int* __restrict__ rel,
                            const int* __restrict__ edge_ab,
                            const int* __restrict__ edge_bc,
                            const int* __restrict__ edge_ac,
                            const float* __restrict__ M2,
                            float* __restrict__ out, int num_tri) {
    const int lane   = threadIdx.x & 63;
    const int wave   = (int)((blockIdx.x * blockDim.x + threadIdx.x) >> 6);
    const int nwaves = (int)((gridDim.x * blockDim.x) >> 6);
    for (int t = wave; t < num_tri; t += nwaves) {
        const int p = rel[edge_ab[t]] * NREL + rel[edge_bc[t]];
        const float v = M2[p * HIDDEN + lane];
        unsafeAtomicAdd(&out[(size_t)edge_ac[t] * HIDDEN + lane], v);
    }
}

__global__ void finalize(const int* __restrict__ rel,
                         const float* __restrict__ Hc,
                         float* __restrict__ out, int num_edge) {
    const int total = num_edge * (HIDDEN / 4);
    int i = blockIdx.x * blockDim.x + threadIdx.x;
    const int stride = gridDim.x * blockDim.x;
    for (; i < total; i += stride) {
        const int e = i >> 4;
        const int q = i & 15;
        float4 a = ((const float4*)out)[i];
        float4 h = ((const float4*)(Hc + rel[e] * HIDDEN))[q];
        float4 o;
        o.x = fmaxf(a.x + h.x, 0.f);
        o.y = fmaxf(a.y + h.y, 0.f);
        o.z = fmaxf(a.z + h.z, 0.f);
        o.w = fmaxf(a.w + h.w, 0.f);
        ((float4*)out)[i] = o;
    }
}
// ---------------------------------------------------------------------------

extern "C" void kernel_launch(void* const* d_in, const int* in_sizes, int n_in,
                              void* d_out, int out_size, void* d_ws, size_t ws_size,
                              hipStream_t stream) {
    const float* rel_emb = (const float*)d_in[0];
    const float* W_msg   = (const float*)d_in[1];
    const float* W_upd   = (const float*)d_in[2];
    const int* rel     = (const int*)d_in[5];
    const int* edge_ab = (const int*)d_in[6];
    const int* edge_bc = (const int*)d_in[7];
    const int* edge_ac = (const int*)d_in[8];
    float* out = (float*)d_out;

    const int num_edge = in_sizes[5];
    const int num_tri  = in_sizes[6];

    // ---- workspace layout (256B-aligned offsets) ----
    char* ws = (char*)d_ws;
    size_t off = 0;
    auto alloc = [&](size_t bytes) { char* p = ws + off; off = (off + bytes + 255) & ~(size_t)255; return p; };
    float*          M2   = (float*)alloc((size_t)NPAIR * HIDDEN * 4);        // 640 KB
    float*          Hc   = (float*)alloc((size_t)NREL * HIDDEN * 4);         // 12.8 KB
    unsigned char*  rel8 = (unsigned char*)alloc((size_t)num_edge);          // 1 MB
    unsigned int*   recA = (unsigned int*)alloc((size_t)num_edge * 16);      // 16 MB
    unsigned short* recB = (unsigned short*)alloc((size_t)num_edge * 48);    // 48 MB
    const size_t required = off;

    const bool fast = (ws_size >= required);

    if (fast) {
        hipMemsetAsync(recA, 0, (size_t)num_edge * 16, stream);
        precompute_tables<<<NPAIR, HIDDEN, 0, stream>>>(rel_emb, W_msg, W_upd,
                                                        rel, rel8, num_edge, M2, Hc);
        const int n8 = num_tri >> 3;
        int hblocks = (n8 + 255) / 256;
        if (hblocks < 1) hblocks = 1;
        hist_record<<<hblocks, 256, 0, stream>>>(rel8, edge_ab, edge_bc, edge_ac,
                                                 recA, recB, num_tri);
        int ablocks = (num_edge + 15) / 16;
        if (ablocks > 16384) ablocks = 16384;
        accumulate_record<<<ablocks, 256, 0, stream>>>(rel8, recA, recB, M2, Hc,
                                                       out, num_edge);
    } else {
        // ---- fallback: atomic scatter path (needs only M2 + Hc) ----
        precompute_tables<<<NPAIR, HIDDEN, 0, stream>>>(rel_emb, W_msg, W_upd,
                                                        rel, (unsigned char*)d_ws, 0, M2, Hc);
        hipMemsetAsync(d_out, 0, (size_t)out_size * sizeof(float), stream);
        scatter_tri<<<8192, 256, 0, stream>>>(rel, edge_ab, edge_bc, edge_ac, M2, out, num_tri);
        const int total4 = num_edge * (HIDDEN / 4);
        int fin_blocks = (total4 + 255) / 256;
        if (fin_blocks > 65535 * 8) fin_blocks = 65535 * 8;
        finalize<<<fin_blocks, 256, 0, stream>>>(rel, Hc, out, num_edge);
    }
}